// Round 8
// baseline (323.420 us; speedup 1.0000x reference)
//
#include <hip/hip_runtime.h>
#include <math.h>

#define DIN 128   // D_IN == D_HID == 128
#define NCLS 64
#define BCAP 5120 // per-bucket capacity: mean 4096, sd 64 -> +16 sigma
#define SCALE1 64.0f   // hs1 fp8 scale
#define SCALE2 256.0f  // hs2 fp8 scale

typedef __attribute__((ext_vector_type(4))) float  f32x4;
typedef __attribute__((ext_vector_type(2))) float  f32x2;
typedef __attribute__((ext_vector_type(8))) short  bf16x8;   // MFMA A/B frag (4 VGPRs)

__device__ inline unsigned short f2bf(float f) {             // round-to-nearest-even
    unsigned int u = __float_as_uint(f);
    u += 0x7fff + ((u >> 16) & 1);
    return (unsigned short)(u >> 16);
}
__device__ inline float bf2f(unsigned int hi) { return __uint_as_float(hi << 16); }

// ---------------- CSR build: bucketed two-phase counting sort ----------------

__global__ __launch_bounds__(256) void binA_k(const int* __restrict__ ei,
                                              int* __restrict__ gcnt,
                                              unsigned int* __restrict__ tmp,
                                              int E, int NB) {
    __shared__ int lcnt[512];
    __shared__ int gpos[512];
    const int t = threadIdx.x;
    for (int i = t; i < NB; i += 256) lcnt[i] = 0;
    __syncthreads();

    const int base = blockIdx.x * 4096;
    unsigned int pk[16];
    short bk[16], rk[16];
#pragma unroll
    for (int k = 0; k < 16; ++k) {
        int e = base + k * 256 + t;
        if (e < E) {
            int s = ei[e];
            int d = ei[E + e];
            int b = d >> 8;
            pk[k] = ((unsigned int)s << 8) | (unsigned int)(d & 255);
            bk[k] = (short)b;
            rk[k] = (short)atomicAdd(&lcnt[b], 1);
        } else {
            bk[k] = -1;
        }
    }
    __syncthreads();
    for (int i = t; i < NB; i += 256)
        gpos[i] = lcnt[i] ? atomicAdd(&gcnt[i], lcnt[i]) : 0;
    __syncthreads();
#pragma unroll
    for (int k = 0; k < 16; ++k) {
        if (bk[k] >= 0) {
            int b = bk[k];
            int pos = gpos[b] + rk[k];
            if (pos < BCAP) tmp[(size_t)b * BCAP + pos] = pk[k];
        }
    }
}

__global__ __launch_bounds__(512) void scanb_k(const int* __restrict__ gcnt,
                                               int* __restrict__ bbase, int NB) {
    __shared__ int tmp[512];
    int t = threadIdx.x;
    int v = (t < NB) ? gcnt[t] : 0;
    tmp[t] = v; __syncthreads();
    for (int o = 1; o < 512; o <<= 1) {
        int x = (t >= o) ? tmp[t - o] : 0;
        __syncthreads();
        tmp[t] += x;
        __syncthreads();
    }
    if (t < NB) bbase[t] = (t == 0) ? 0 : tmp[t - 1];
}

// one block per bucket: counting sort by dst&255, then per-node src-sort, emit CSR + dinv
__global__ __launch_bounds__(256) void binB_k(const unsigned int* __restrict__ tmp,
                                              const int* __restrict__ gcnt,
                                              const int* __restrict__ bbase,
                                              int* __restrict__ off,
                                              float* __restrict__ dinv,
                                              int* __restrict__ srcs,
                                              int N, int E) {
    __shared__ unsigned int stg[BCAP];
    __shared__ unsigned int sorted[BCAP];
    __shared__ int lcnt[256], sc[256], loff[256], lcur[256];
    const int b = blockIdx.x, t = threadIdx.x;
    int cnt = gcnt[b];
    if (cnt > BCAP) cnt = BCAP;
    const int base = bbase[b];
    lcnt[t] = 0; lcur[t] = 0;
    __syncthreads();
    for (int i = t; i < cnt; i += 256) {
        unsigned int v = tmp[(size_t)b * BCAP + i];
        stg[i] = v;
        atomicAdd(&lcnt[v & 255u], 1);
    }
    __syncthreads();
    sc[t] = lcnt[t]; __syncthreads();
    for (int o = 1; o < 256; o <<= 1) {
        int x = (t >= o) ? sc[t - o] : 0;
        __syncthreads();
        sc[t] += x;
        __syncthreads();
    }
    int excl = (t == 0) ? 0 : sc[t - 1];
    loff[t] = excl;
    int node = b * 256 + t;
    if (node <= N) off[node] = base + excl;
    if (node < N)  dinv[node] = rsqrtf(1.0f + (float)lcnt[t]);
    __syncthreads();
    // place into per-node contiguous lists (src only)
    for (int i = t; i < cnt; i += 256) {
        unsigned int v = stg[i];
        int l = v & 255u;
        int r = atomicAdd(&lcur[l], 1);
        sorted[loff[l] + r] = v >> 8;
    }
    __syncthreads();
    // per-thread insertion sort of this node's list (ascending src)
    {
        int s0 = loff[t], n = lcnt[t];
        for (int i = 1; i < n; ++i) {
            unsigned int key = sorted[s0 + i];
            int j = i - 1;
            while (j >= 0 && sorted[s0 + j] > key) {
                sorted[s0 + j + 1] = sorted[s0 + j];
                --j;
            }
            sorted[s0 + j + 1] = key;
        }
    }
    __syncthreads();
    for (int i = t; i < cnt; i += 256) srcs[base + i] = (int)sorted[i];
}

// ---------------- W prep: transpose + cast to bf16 ----------------

__global__ void wprep_k(const float* __restrict__ W1, const float* __restrict__ W2,
                        unsigned short* __restrict__ wt1, unsigned short* __restrict__ wt2) {
    int i = blockIdx.x * 256 + threadIdx.x;
    if (i < 128 * 128) { int k = i >> 7, n = i & 127; wt1[n * 128 + k] = f2bf(W1[i]); }
    if (i < 128 * 64)  { int k = i >> 6, n = i & 63;  wt2[n * 128 + k] = f2bf(W2[i]); }
}

// ---------------- MFMA bf16 GEMM -> fp8 out: C[r,:] = fp8(oscale * dinv[r] * (A[r,:] @ B)) ----------------

template<int BN, bool AFP32>
__global__ __launch_bounds__(256) void mgemm_k(const void* __restrict__ Ap,
                                               const unsigned short* __restrict__ Bt,
                                               const float* __restrict__ dinv,
                                               unsigned char* __restrict__ C,
                                               float oscale, int N) {
    constexpr int LDK = DIN + 8;
    __shared__ unsigned short As[128 * LDK];
    __shared__ unsigned short Bs[BN * LDK];
    const int tid  = threadIdx.x;
    const int row0 = blockIdx.x * 128;

    for (int idx = tid; idx < BN * 16; idx += 256) {
        int n = idx >> 4, c = (idx & 15) << 3;
        *(uint4*)&Bs[n * LDK + c] = *(const uint4*)&Bt[n * DIN + c];
    }
    for (int idx = tid; idx < 128 * 16; idx += 256) {
        int r = idx >> 4, c = (idx & 15) << 3;
        int gr = row0 + r;
        if (AFP32) {
            unsigned short v[8];
            if (gr < N) {
                const float* A = (const float*)Ap;
                f32x4 a0 = *(const f32x4*)&A[(size_t)gr * DIN + c];
                f32x4 a1 = *(const f32x4*)&A[(size_t)gr * DIN + c + 4];
                v[0] = f2bf(a0.x); v[1] = f2bf(a0.y); v[2] = f2bf(a0.z); v[3] = f2bf(a0.w);
                v[4] = f2bf(a1.x); v[5] = f2bf(a1.y); v[6] = f2bf(a1.z); v[7] = f2bf(a1.w);
            } else {
#pragma unroll
                for (int j = 0; j < 8; ++j) v[j] = 0;
            }
            *(uint4*)&As[r * LDK + c] = *(const uint4*)v;
        } else {
            uint4 v = make_uint4(0, 0, 0, 0);
            if (gr < N) v = *(const uint4*)&((const unsigned short*)Ap)[(size_t)gr * DIN + c];
            *(uint4*)&As[r * LDK + c] = v;
        }
    }
    __syncthreads();

    const int wave = tid >> 6, lane = tid & 63;
    const int lrow = lane & 15, kq = lane >> 4;
    constexpr int NT = BN / 16;
    f32x4 acc[2][NT];
#pragma unroll
    for (int m = 0; m < 2; ++m)
#pragma unroll
        for (int t = 0; t < NT; ++t) acc[m][t] = (f32x4){0.f, 0.f, 0.f, 0.f};

    const unsigned short* Abase = &As[(wave * 32 + lrow) * LDK + kq * 8];
    const unsigned short* Bbase = &Bs[lrow * LDK + kq * 8];
#pragma unroll
    for (int kk = 0; kk < 4; ++kk) {
        bf16x8 a0 = *(const bf16x8*)(Abase + kk * 32);
        bf16x8 a1 = *(const bf16x8*)(Abase + 16 * LDK + kk * 32);
        bf16x8 bfr[NT];
#pragma unroll
        for (int t = 0; t < NT; ++t)
            bfr[t] = *(const bf16x8*)(Bbase + t * 16 * LDK + kk * 32);
#pragma unroll
        for (int t = 0; t < NT; ++t) {
            acc[0][t] = __builtin_amdgcn_mfma_f32_16x16x32_bf16(a0, bfr[t], acc[0][t], 0, 0, 0);
            acc[1][t] = __builtin_amdgcn_mfma_f32_16x16x32_bf16(a1, bfr[t], acc[1][t], 0, 0, 0);
        }
    }

#pragma unroll
    for (int tm = 0; tm < 2; ++tm) {
        int rb = row0 + wave * 32 + tm * 16 + kq * 4;
#pragma unroll
        for (int r = 0; r < 4; ++r) {
            int gr = rb + r;
            if (gr < N) {
                float sc2 = dinv[gr] * oscale;
#pragma unroll
                for (int t = 0; t < NT; t += 2) {
                    int pk = __builtin_amdgcn_cvt_pk_fp8_f32(acc[tm][t][r] * sc2,
                                                             acc[tm][t + 1][r] * sc2, 0, false);
                    C[(size_t)gr * BN + t * 16 + lrow]       = (unsigned char)(pk & 0xff);
                    C[(size_t)gr * BN + (t + 1) * 16 + lrow] = (unsigned char)((pk >> 8) & 0xff);
                }
            }
        }
    }
}

// ---------------- gather layer 1 (fp8 in, bf16 out): one wave/node, 32-lane halves ----------------
// packed f32x2 accumulation; 8 edges in flight per half (16 per wave) in main loop.

__global__ __launch_bounds__(256) void gather1_k(const unsigned char* __restrict__ hs,
                                                 const int* __restrict__ off,
                                                 const int* __restrict__ srcs,
                                                 const float* __restrict__ dinv,
                                                 const float* __restrict__ b1,
                                                 unsigned short* __restrict__ outp, int N) {
    int node = blockIdx.x * 4 + (threadIdx.x >> 6);
    if (node >= N) return;
    int lane = threadIdx.x & 63;
    int half = lane >> 5;
    int sl   = lane & 31;
    int beg = off[node], end = off[node + 1];
    const unsigned int* hp = (const unsigned int*)hs;   // row = 32 dwords (4 fp8 each)
    f32x2 A = {0.f, 0.f}, Ah = {0.f, 0.f};
    f32x2 C = {0.f, 0.f}, Ch = {0.f, 0.f};
    int idx = beg + half;
    // main: 8 rows per half per iteration (16 per wave)
    for (; idx + 14 < end; idx += 16) {
        int s[8];
#pragma unroll
        for (int k = 0; k < 8; ++k) s[k] = srcs[idx + 2 * k];
        unsigned int v[8];
#pragma unroll
        for (int k = 0; k < 8; ++k) v[k] = hp[(size_t)s[k] * 32 + sl];
#pragma unroll
        for (int k = 0; k < 8; k += 2) {
            A  += __builtin_amdgcn_cvt_pk_f32_fp8((int)v[k], false);
            Ah += __builtin_amdgcn_cvt_pk_f32_fp8((int)v[k], true);
            C  += __builtin_amdgcn_cvt_pk_f32_fp8((int)v[k + 1], false);
            Ch += __builtin_amdgcn_cvt_pk_f32_fp8((int)v[k + 1], true);
        }
    }
    // mid: 4 rows per half
    for (; idx + 6 < end; idx += 8) {
        int s0 = srcs[idx], s1 = srcs[idx + 2], s2 = srcs[idx + 4], s3 = srcs[idx + 6];
        unsigned int v0 = hp[(size_t)s0 * 32 + sl];
        unsigned int v1 = hp[(size_t)s1 * 32 + sl];
        unsigned int v2 = hp[(size_t)s2 * 32 + sl];
        unsigned int v3 = hp[(size_t)s3 * 32 + sl];
        A  += __builtin_amdgcn_cvt_pk_f32_fp8((int)v0, false);
        Ah += __builtin_amdgcn_cvt_pk_f32_fp8((int)v0, true);
        C  += __builtin_amdgcn_cvt_pk_f32_fp8((int)v1, false);
        Ch += __builtin_amdgcn_cvt_pk_f32_fp8((int)v1, true);
        A  += __builtin_amdgcn_cvt_pk_f32_fp8((int)v2, false);
        Ah += __builtin_amdgcn_cvt_pk_f32_fp8((int)v2, true);
        C  += __builtin_amdgcn_cvt_pk_f32_fp8((int)v3, false);
        Ch += __builtin_amdgcn_cvt_pk_f32_fp8((int)v3, true);
    }
    for (; idx <= end; idx += 2) {                      // virtual list: index end == self-loop
        int s = (idx < end) ? srcs[idx] : node;
        unsigned int v = hp[(size_t)s * 32 + sl];
        A  += __builtin_amdgcn_cvt_pk_f32_fp8((int)v, false);
        Ah += __builtin_amdgcn_cvt_pk_f32_fp8((int)v, true);
    }
    A += C; Ah += Ch;
    float a0 = A.x, a1 = A.y, a2 = Ah.x, a3 = Ah.y;
    a0 += __shfl_xor(a0, 32, 64);
    a1 += __shfl_xor(a1, 32, 64);
    a2 += __shfl_xor(a2, 32, 64);
    a3 += __shfl_xor(a3, 32, 64);
    if (half == 0) {
        float d = dinv[node] * (1.0f / SCALE1);
        float4 b = ((const float4*)b1)[sl];
        float o0 = fmaxf(fmaf(d, a0, b.x), 0.f);
        float o1 = fmaxf(fmaf(d, a1, b.y), 0.f);
        float o2 = fmaxf(fmaf(d, a2, b.z), 0.f);
        float o3 = fmaxf(fmaf(d, a3, b.w), 0.f);
        uint2 o;
        o.x = (unsigned int)f2bf(o0) | ((unsigned int)f2bf(o1) << 16);
        o.y = (unsigned int)f2bf(o2) | ((unsigned int)f2bf(o3) << 16);
        ((uint2*)outp)[(size_t)node * 32 + sl] = o;
    }
}

// ---------------- gather layer 2 + log_softmax (fp8 in): one wave/node, 16-lane quarters ----------------

__global__ __launch_bounds__(256) void gather2_k(const unsigned char* __restrict__ hs,
                                                 const int* __restrict__ off,
                                                 const int* __restrict__ srcs,
                                                 const float* __restrict__ dinv,
                                                 const float* __restrict__ b2,
                                                 float* __restrict__ out, int N) {
    int node = blockIdx.x * 4 + (threadIdx.x >> 6);
    if (node >= N) return;
    int lane = threadIdx.x & 63;
    int q  = lane >> 4;
    int sl = lane & 15;
    int beg = off[node], end = off[node + 1];
    const unsigned int* hp = (const unsigned int*)hs;   // row = 16 dwords
    f32x2 A = {0.f, 0.f}, Ah = {0.f, 0.f};
    f32x2 C = {0.f, 0.f}, Ch = {0.f, 0.f};
    int idx = beg + q;
    // main: 4 rows per quarter per iteration (16 per wave)
    for (; idx + 12 < end; idx += 16) {
        int s0 = srcs[idx], s1 = srcs[idx + 4], s2 = srcs[idx + 8], s3 = srcs[idx + 12];
        unsigned int v0 = hp[(size_t)s0 * 16 + sl];
        unsigned int v1 = hp[(size_t)s1 * 16 + sl];
        unsigned int v2 = hp[(size_t)s2 * 16 + sl];
        unsigned int v3 = hp[(size_t)s3 * 16 + sl];
        A  += __builtin_amdgcn_cvt_pk_f32_fp8((int)v0, false);
        Ah += __builtin_amdgcn_cvt_pk_f32_fp8((int)v0, true);
        C  += __builtin_amdgcn_cvt_pk_f32_fp8((int)v1, false);
        Ch += __builtin_amdgcn_cvt_pk_f32_fp8((int)v1, true);
        A  += __builtin_amdgcn_cvt_pk_f32_fp8((int)v2, false);
        Ah += __builtin_amdgcn_cvt_pk_f32_fp8((int)v2, true);
        C  += __builtin_amdgcn_cvt_pk_f32_fp8((int)v3, false);
        Ch += __builtin_amdgcn_cvt_pk_f32_fp8((int)v3, true);
    }
    for (; idx <= end; idx += 4) {
        int s = (idx < end) ? srcs[idx] : node;
        unsigned int v = hp[(size_t)s * 16 + sl];
        A  += __builtin_amdgcn_cvt_pk_f32_fp8((int)v, false);
        Ah += __builtin_amdgcn_cvt_pk_f32_fp8((int)v, true);
    }
    A += C; Ah += Ch;
    float a0 = A.x, a1 = A.y, a2 = Ah.x, a3 = Ah.y;
    a0 += __shfl_xor(a0, 16, 64); a0 += __shfl_xor(a0, 32, 64);
    a1 += __shfl_xor(a1, 16, 64); a1 += __shfl_xor(a1, 32, 64);
    a2 += __shfl_xor(a2, 16, 64); a2 += __shfl_xor(a2, 32, 64);
    a3 += __shfl_xor(a3, 16, 64); a3 += __shfl_xor(a3, 32, 64);
    if (q == 0) {
        float d = dinv[node] * (1.0f / SCALE2);
        float4 b = ((const float4*)b2)[sl];
        float v0 = fmaf(d, a0, b.x);
        float v1 = fmaf(d, a1, b.y);
        float v2 = fmaf(d, a2, b.z);
        float v3 = fmaf(d, a3, b.w);
        float m = fmaxf(fmaxf(v0, v1), fmaxf(v2, v3));
#pragma unroll
        for (int o = 8; o > 0; o >>= 1) m = fmaxf(m, __shfl_xor(m, o, 16));
        float s = expf(v0 - m) + expf(v1 - m) + expf(v2 - m) + expf(v3 - m);
#pragma unroll
        for (int o = 8; o > 0; o >>= 1) s += __shfl_xor(s, o, 16);
        float ls = logf(s);
        float4 o4;
        o4.x = v0 - m - ls; o4.y = v1 - m - ls; o4.z = v2 - m - ls; o4.w = v3 - m - ls;
        ((float4*)out)[(size_t)node * 16 + sl] = o4;
    }
}

// ---------------- launch ----------------

extern "C" void kernel_launch(void* const* d_in, const int* in_sizes, int n_in,
                              void* d_out, int out_size, void* d_ws, size_t ws_size,
                              hipStream_t stream) {
    const float* x  = (const float*)d_in[0];
    const int*   ei = (const int*)d_in[1];
    const float* W1 = (const float*)d_in[2];
    const float* b1 = (const float*)d_in[3];
    const float* W2 = (const float*)d_in[4];
    const float* b2 = (const float*)d_in[5];
    float* out = (float*)d_out;

    const int N  = in_sizes[0] / DIN;
    const int E  = in_sizes[1] / 2;
    const int NB = (N + 255) >> 8;

    char* p = (char*)d_ws;
    auto alloc = [&](size_t bytes) { void* r = p; p += (bytes + 255) & ~(size_t)255; return r; };
    float* dinv  = (float*)alloc((size_t)N * 4);
    int*   gcnt  = (int*)  alloc((size_t)NB * 4);
    int*   bbase = (int*)  alloc((size_t)NB * 4);
    int*   off   = (int*)  alloc((size_t)(N + 1) * 4);
    int*   srcs  = (int*)  alloc((size_t)E * 4);
    unsigned int* tmp = (unsigned int*)alloc((size_t)NB * BCAP * 4);
    unsigned short* wt1 = (unsigned short*)alloc(128 * 128 * 2);
    unsigned short* wt2 = (unsigned short*)alloc(64 * 128 * 2);
    unsigned char*  hs1 = (unsigned char*)alloc((size_t)N * DIN);   // fp8
    unsigned short* h1p = (unsigned short*)alloc((size_t)N * DIN * 2);
    unsigned char*  hs2 = (unsigned char*)alloc((size_t)N * NCLS);  // fp8

    wprep_k<<<64, 256, 0, stream>>>(W1, W2, wt1, wt2);
    hipMemsetAsync(gcnt, 0, (size_t)NB * 4, stream);
    binA_k<<<(E + 4095) / 4096, 256, 0, stream>>>(ei, gcnt, tmp, E, NB);
    scanb_k<<<1, 512, 0, stream>>>(gcnt, bbase, NB);
    binB_k<<<NB, 256, 0, stream>>>(tmp, gcnt, bbase, off, dinv, srcs, N, E);

    mgemm_k<DIN, true><<<(N + 127) / 128, 256, 0, stream>>>(x, wt1, dinv, hs1, SCALE1, N);
    gather1_k<<<(N + 3) / 4, 256, 0, stream>>>(hs1, off, srcs, dinv, b1, h1p, N);

    mgemm_k<NCLS, false><<<(N + 127) / 128, 256, 0, stream>>>(h1p, wt2, dinv, hs2, SCALE2, N);
    gather2_k<<<(N + 3) / 4, 256, 0, stream>>>(hs2, off, srcs, dinv, b2, out, N);
}

// Round 9
// 280.731 us; speedup vs baseline: 1.1521x; 1.1521x over previous
//
#include <hip/hip_runtime.h>
#include <math.h>

#define DIN 128   // D_IN == D_HID == 128
#define NCLS 64
#define BCAP 5120 // per-bucket capacity: mean 4096, sd 64 -> +16 sigma
#define SCALE1 64.0f   // hs1 fp8 scale
#define SCALE2 256.0f  // hs2 fp8 scale

typedef __attribute__((ext_vector_type(4))) float  f32x4;
typedef __attribute__((ext_vector_type(2))) float  f32x2;
typedef __attribute__((ext_vector_type(8))) short  bf16x8;   // MFMA A/B frag (4 VGPRs)

__device__ inline unsigned short f2bf(float f) {             // round-to-nearest-even
    unsigned int u = __float_as_uint(f);
    u += 0x7fff + ((u >> 16) & 1);
    return (unsigned short)(u >> 16);
}

// ---------------- CSR build: bucketed two-phase counting sort ----------------

__global__ __launch_bounds__(256) void binA_k(const int* __restrict__ ei,
                                              int* __restrict__ gcnt,
                                              unsigned int* __restrict__ tmp,
                                              int E, int NB) {
    __shared__ int lcnt[512];
    __shared__ int gpos[512];
    const int t = threadIdx.x;
    for (int i = t; i < NB; i += 256) lcnt[i] = 0;
    __syncthreads();

    const int base = blockIdx.x * 4096;
    unsigned int pk[16];
    short bk[16], rk[16];
#pragma unroll
    for (int k = 0; k < 16; ++k) {
        int e = base + k * 256 + t;
        if (e < E) {
            int s = ei[e];
            int d = ei[E + e];
            int b = d >> 8;
            pk[k] = ((unsigned int)s << 8) | (unsigned int)(d & 255);
            bk[k] = (short)b;
            rk[k] = (short)atomicAdd(&lcnt[b], 1);
        } else {
            bk[k] = -1;
        }
    }
    __syncthreads();
    for (int i = t; i < NB; i += 256)
        gpos[i] = lcnt[i] ? atomicAdd(&gcnt[i], lcnt[i]) : 0;
    __syncthreads();
#pragma unroll
    for (int k = 0; k < 16; ++k) {
        if (bk[k] >= 0) {
            int b = bk[k];
            int pos = gpos[b] + rk[k];
            if (pos < BCAP) tmp[(size_t)b * BCAP + pos] = pk[k];
        }
    }
}

__global__ __launch_bounds__(512) void scanb_k(const int* __restrict__ gcnt,
                                               int* __restrict__ bbase, int NB) {
    __shared__ int tmp[512];
    int t = threadIdx.x;
    int v = (t < NB) ? gcnt[t] : 0;
    tmp[t] = v; __syncthreads();
    for (int o = 1; o < 512; o <<= 1) {
        int x = (t >= o) ? tmp[t - o] : 0;
        __syncthreads();
        tmp[t] += x;
        __syncthreads();
    }
    if (t < NB) bbase[t] = (t == 0) ? 0 : tmp[t - 1];
}

// one block per bucket: counting sort by dst&255, emit CSR + dinv (R7 version, no src-sort)
__global__ __launch_bounds__(256) void binB_k(const unsigned int* __restrict__ tmp,
                                              const int* __restrict__ gcnt,
                                              const int* __restrict__ bbase,
                                              int* __restrict__ off,
                                              float* __restrict__ dinv,
                                              int* __restrict__ srcs,
                                              int N, int E) {
    __shared__ unsigned int stg[BCAP];
    __shared__ int lcnt[256], sc[256], loff[256], lcur[256];
    const int b = blockIdx.x, t = threadIdx.x;
    int cnt = gcnt[b];
    if (cnt > BCAP) cnt = BCAP;
    const int base = bbase[b];
    lcnt[t] = 0; lcur[t] = 0;
    __syncthreads();
    for (int i = t; i < cnt; i += 256) {
        unsigned int v = tmp[(size_t)b * BCAP + i];
        stg[i] = v;
        atomicAdd(&lcnt[v & 255u], 1);
    }
    __syncthreads();
    sc[t] = lcnt[t]; __syncthreads();
    for (int o = 1; o < 256; o <<= 1) {
        int x = (t >= o) ? sc[t - o] : 0;
        __syncthreads();
        sc[t] += x;
        __syncthreads();
    }
    int excl = (t == 0) ? 0 : sc[t - 1];
    loff[t] = excl;
    int node = b * 256 + t;
    if (node <= N) off[node] = base + excl;
    if (node < N)  dinv[node] = rsqrtf(1.0f + (float)lcnt[t]);
    __syncthreads();
    for (int i = t; i < cnt; i += 256) {
        unsigned int v = stg[i];
        int l = v & 255u;
        int r = atomicAdd(&lcur[l], 1);
        srcs[base + loff[l] + r] = (int)(v >> 8);
    }
}

// ---------------- W prep: transpose + cast to bf16 ----------------

__global__ void wprep_k(const float* __restrict__ W1, const float* __restrict__ W2,
                        unsigned short* __restrict__ wt1, unsigned short* __restrict__ wt2) {
    int i = blockIdx.x * 256 + threadIdx.x;
    if (i < 128 * 128) { int k = i >> 7, n = i & 127; wt1[n * 128 + k] = f2bf(W1[i]); }
    if (i < 128 * 64)  { int k = i >> 6, n = i & 63;  wt2[n * 128 + k] = f2bf(W2[i]); }
}

// ---------------- MFMA bf16 GEMM -> fp8 out: C[r,:] = fp8(oscale * dinv[r] * (A[r,:] @ B)) ----------------

template<int BN, bool AFP32>
__global__ __launch_bounds__(256) void mgemm_k(const void* __restrict__ Ap,
                                               const unsigned short* __restrict__ Bt,
                                               const float* __restrict__ dinv,
                                               unsigned char* __restrict__ C,
                                               float oscale, int N) {
    constexpr int LDK = DIN + 8;
    __shared__ unsigned short As[128 * LDK];
    __shared__ unsigned short Bs[BN * LDK];
    const int tid  = threadIdx.x;
    const int row0 = blockIdx.x * 128;

    for (int idx = tid; idx < BN * 16; idx += 256) {
        int n = idx >> 4, c = (idx & 15) << 3;
        *(uint4*)&Bs[n * LDK + c] = *(const uint4*)&Bt[n * DIN + c];
    }
    for (int idx = tid; idx < 128 * 16; idx += 256) {
        int r = idx >> 4, c = (idx & 15) << 3;
        int gr = row0 + r;
        if (AFP32) {
            unsigned short v[8];
            if (gr < N) {
                const float* A = (const float*)Ap;
                f32x4 a0 = *(const f32x4*)&A[(size_t)gr * DIN + c];
                f32x4 a1 = *(const f32x4*)&A[(size_t)gr * DIN + c + 4];
                v[0] = f2bf(a0.x); v[1] = f2bf(a0.y); v[2] = f2bf(a0.z); v[3] = f2bf(a0.w);
                v[4] = f2bf(a1.x); v[5] = f2bf(a1.y); v[6] = f2bf(a1.z); v[7] = f2bf(a1.w);
            } else {
#pragma unroll
                for (int j = 0; j < 8; ++j) v[j] = 0;
            }
            *(uint4*)&As[r * LDK + c] = *(const uint4*)v;
        } else {
            uint4 v = make_uint4(0, 0, 0, 0);
            if (gr < N) v = *(const uint4*)&((const unsigned short*)Ap)[(size_t)gr * DIN + c];
            *(uint4*)&As[r * LDK + c] = v;
        }
    }
    __syncthreads();

    const int wave = tid >> 6, lane = tid & 63;
    const int lrow = lane & 15, kq = lane >> 4;
    constexpr int NT = BN / 16;
    f32x4 acc[2][NT];
#pragma unroll
    for (int m = 0; m < 2; ++m)
#pragma unroll
        for (int t = 0; t < NT; ++t) acc[m][t] = (f32x4){0.f, 0.f, 0.f, 0.f};

    const unsigned short* Abase = &As[(wave * 32 + lrow) * LDK + kq * 8];
    const unsigned short* Bbase = &Bs[lrow * LDK + kq * 8];
#pragma unroll
    for (int kk = 0; kk < 4; ++kk) {
        bf16x8 a0 = *(const bf16x8*)(Abase + kk * 32);
        bf16x8 a1 = *(const bf16x8*)(Abase + 16 * LDK + kk * 32);
        bf16x8 bfr[NT];
#pragma unroll
        for (int t = 0; t < NT; ++t)
            bfr[t] = *(const bf16x8*)(Bbase + t * 16 * LDK + kk * 32);
#pragma unroll
        for (int t = 0; t < NT; ++t) {
            acc[0][t] = __builtin_amdgcn_mfma_f32_16x16x32_bf16(a0, bfr[t], acc[0][t], 0, 0, 0);
            acc[1][t] = __builtin_amdgcn_mfma_f32_16x16x32_bf16(a1, bfr[t], acc[1][t], 0, 0, 0);
        }
    }

#pragma unroll
    for (int tm = 0; tm < 2; ++tm) {
        int rb = row0 + wave * 32 + tm * 16 + kq * 4;
#pragma unroll
        for (int r = 0; r < 4; ++r) {
            int gr = rb + r;
            if (gr < N) {
                float sc2 = dinv[gr] * oscale;
#pragma unroll
                for (int t = 0; t < NT; t += 2) {
                    int pk = __builtin_amdgcn_cvt_pk_fp8_f32(acc[tm][t][r] * sc2,
                                                             acc[tm][t + 1][r] * sc2, 0, false);
                    C[(size_t)gr * BN + t * 16 + lrow]       = (unsigned char)(pk & 0xff);
                    C[(size_t)gr * BN + (t + 1) * 16 + lrow] = (unsigned char)((pk >> 8) & 0xff);
                }
            }
        }
    }
}

__device__ inline void dec8(uint2 v, f32x2& x0, f32x2& x1, f32x2& x2, f32x2& x3) {
    x0 += __builtin_amdgcn_cvt_pk_f32_fp8((int)v.x, false);
    x1 += __builtin_amdgcn_cvt_pk_f32_fp8((int)v.x, true);
    x2 += __builtin_amdgcn_cvt_pk_f32_fp8((int)v.y, false);
    x3 += __builtin_amdgcn_cvt_pk_f32_fp8((int)v.y, true);
}

// ---------------- gather layer 1 (fp8 in, bf16 out): 16-lane quarters, dwordx2/lane ----------------
// quarter q handles virtual edge indices beg+q, +4, ... ; index==end is the self-loop.
// lane sl (0..15) covers cols 8*sl .. 8*sl+7.

__global__ __launch_bounds__(256) void gather1_k(const unsigned char* __restrict__ hs,
                                                 const int* __restrict__ off,
                                                 const int* __restrict__ srcs,
                                                 const float* __restrict__ dinv,
                                                 const float* __restrict__ b1,
                                                 unsigned short* __restrict__ outp, int N) {
    int node = blockIdx.x * 4 + (threadIdx.x >> 6);
    if (node >= N) return;
    int lane = threadIdx.x & 63;
    int q  = lane >> 4;
    int sl = lane & 15;
    int beg = off[node], end = off[node + 1];
    const uint2* hp = (const uint2*)hs;            // row = 16 x uint2 (8 fp8 each)
    f32x2 A0 = {0.f,0.f}, A1 = {0.f,0.f}, A2 = {0.f,0.f}, A3 = {0.f,0.f};
    f32x2 C0 = {0.f,0.f}, C1 = {0.f,0.f}, C2 = {0.f,0.f}, C3 = {0.f,0.f};
    int idx = beg + q;
    // main: 4 edges per quarter per iteration (16 in flight per wave)
    for (; idx + 12 < end; idx += 16) {
        unsigned s0 = (unsigned)srcs[idx],     s1 = (unsigned)srcs[idx + 4];
        unsigned s2 = (unsigned)srcs[idx + 8], s3 = (unsigned)srcs[idx + 12];
        uint2 v0 = hp[s0 * 16u + sl];
        uint2 v1 = hp[s1 * 16u + sl];
        uint2 v2 = hp[s2 * 16u + sl];
        uint2 v3 = hp[s3 * 16u + sl];
        dec8(v0, A0, A1, A2, A3);
        dec8(v1, C0, C1, C2, C3);
        dec8(v2, A0, A1, A2, A3);
        dec8(v3, C0, C1, C2, C3);
    }
    for (; idx <= end; idx += 4) {                 // virtual list: index end == self-loop
        unsigned s = (idx < end) ? (unsigned)srcs[idx] : (unsigned)node;
        uint2 v = hp[s * 16u + sl];
        dec8(v, A0, A1, A2, A3);
    }
    A0 += C0; A1 += C1; A2 += C2; A3 += C3;
    // fold quarters (masks 16, 32), component-wise
#pragma unroll
    for (int m = 16; m <= 32; m <<= 1) {
        A0.x += __shfl_xor(A0.x, m, 64); A0.y += __shfl_xor(A0.y, m, 64);
        A1.x += __shfl_xor(A1.x, m, 64); A1.y += __shfl_xor(A1.y, m, 64);
        A2.x += __shfl_xor(A2.x, m, 64); A2.y += __shfl_xor(A2.y, m, 64);
        A3.x += __shfl_xor(A3.x, m, 64); A3.y += __shfl_xor(A3.y, m, 64);
    }
    if (q == 0) {
        float d = dinv[node] * (1.0f / SCALE1);
        float4 ba = ((const float4*)b1)[sl * 2];
        float4 bb = ((const float4*)b1)[sl * 2 + 1];
        float o0 = fmaxf(fmaf(d, A0.x, ba.x), 0.f);
        float o1 = fmaxf(fmaf(d, A0.y, ba.y), 0.f);
        float o2 = fmaxf(fmaf(d, A1.x, ba.z), 0.f);
        float o3 = fmaxf(fmaf(d, A1.y, ba.w), 0.f);
        float o4 = fmaxf(fmaf(d, A2.x, bb.x), 0.f);
        float o5 = fmaxf(fmaf(d, A2.y, bb.y), 0.f);
        float o6 = fmaxf(fmaf(d, A3.x, bb.z), 0.f);
        float o7 = fmaxf(fmaf(d, A3.y, bb.w), 0.f);
        uint4 o;
        o.x = (unsigned)f2bf(o0) | ((unsigned)f2bf(o1) << 16);
        o.y = (unsigned)f2bf(o2) | ((unsigned)f2bf(o3) << 16);
        o.z = (unsigned)f2bf(o4) | ((unsigned)f2bf(o5) << 16);
        o.w = (unsigned)f2bf(o6) | ((unsigned)f2bf(o7) << 16);
        ((uint4*)outp)[(unsigned)node * 16u + sl] = o;
    }
}

// ---------------- gather layer 2 + log_softmax (fp8 in): 8-lane octets, dwordx2/lane ----------------
// octet o handles virtual edge indices beg+o, +8, ...; lane sl (0..7) covers cols 8*sl..8*sl+7.

__global__ __launch_bounds__(256) void gather2_k(const unsigned char* __restrict__ hs,
                                                 const int* __restrict__ off,
                                                 const int* __restrict__ srcs,
                                                 const float* __restrict__ dinv,
                                                 const float* __restrict__ b2,
                                                 float* __restrict__ out, int N) {
    int node = blockIdx.x * 4 + (threadIdx.x >> 6);
    if (node >= N) return;
    int lane = threadIdx.x & 63;
    int o8 = lane >> 3;
    int sl = lane & 7;
    int beg = off[node], end = off[node + 1];
    const uint2* hp = (const uint2*)hs;            // row = 8 x uint2
    f32x2 A0 = {0.f,0.f}, A1 = {0.f,0.f}, A2 = {0.f,0.f}, A3 = {0.f,0.f};
    f32x2 C0 = {0.f,0.f}, C1 = {0.f,0.f}, C2 = {0.f,0.f}, C3 = {0.f,0.f};
    int idx = beg + o8;
    // main: 2 edges per octet per iteration (16 in flight per wave)
    for (; idx + 8 < end; idx += 16) {
        unsigned s0 = (unsigned)srcs[idx], s1 = (unsigned)srcs[idx + 8];
        uint2 v0 = hp[s0 * 8u + sl];
        uint2 v1 = hp[s1 * 8u + sl];
        dec8(v0, A0, A1, A2, A3);
        dec8(v1, C0, C1, C2, C3);
    }
    for (; idx <= end; idx += 8) {                 // virtual list: index end == self-loop
        unsigned s = (idx < end) ? (unsigned)srcs[idx] : (unsigned)node;
        uint2 v = hp[s * 8u + sl];
        dec8(v, A0, A1, A2, A3);
    }
    A0 += C0; A1 += C1; A2 += C2; A3 += C3;
    // fold octets (masks 8, 16, 32)
#pragma unroll
    for (int m = 8; m <= 32; m <<= 1) {
        A0.x += __shfl_xor(A0.x, m, 64); A0.y += __shfl_xor(A0.y, m, 64);
        A1.x += __shfl_xor(A1.x, m, 64); A1.y += __shfl_xor(A1.y, m, 64);
        A2.x += __shfl_xor(A2.x, m, 64); A2.y += __shfl_xor(A2.y, m, 64);
        A3.x += __shfl_xor(A3.x, m, 64); A3.y += __shfl_xor(A3.y, m, 64);
    }
    // every lane now has full sums for its 8 cols; softmax across sl = 0..7 (masks 1,2,4)
    float d = dinv[node] * (1.0f / SCALE2);
    float4 ba = ((const float4*)b2)[sl * 2];
    float4 bb = ((const float4*)b2)[sl * 2 + 1];
    float v0 = fmaf(d, A0.x, ba.x);
    float v1 = fmaf(d, A0.y, ba.y);
    float v2 = fmaf(d, A1.x, ba.z);
    float v3 = fmaf(d, A1.y, ba.w);
    float v4 = fmaf(d, A2.x, bb.x);
    float v5 = fmaf(d, A2.y, bb.y);
    float v6 = fmaf(d, A3.x, bb.z);
    float v7 = fmaf(d, A3.y, bb.w);
    float m = fmaxf(fmaxf(fmaxf(v0, v1), fmaxf(v2, v3)), fmaxf(fmaxf(v4, v5), fmaxf(v6, v7)));
#pragma unroll
    for (int mk = 1; mk <= 4; mk <<= 1) m = fmaxf(m, __shfl_xor(m, mk, 64));
    float s = expf(v0 - m) + expf(v1 - m) + expf(v2 - m) + expf(v3 - m)
            + expf(v4 - m) + expf(v5 - m) + expf(v6 - m) + expf(v7 - m);
#pragma unroll
    for (int mk = 1; mk <= 4; mk <<= 1) s += __shfl_xor(s, mk, 64);
    float ls = m + logf(s);
    if (o8 == 0) {
        float4 oa, ob;
        oa.x = v0 - ls; oa.y = v1 - ls; oa.z = v2 - ls; oa.w = v3 - ls;
        ob.x = v4 - ls; ob.y = v5 - ls; ob.z = v6 - ls; ob.w = v7 - ls;
        ((float4*)out)[(unsigned)node * 16u + sl * 2]     = oa;
        ((float4*)out)[(unsigned)node * 16u + sl * 2 + 1] = ob;
    }
}

// ---------------- launch ----------------

extern "C" void kernel_launch(void* const* d_in, const int* in_sizes, int n_in,
                              void* d_out, int out_size, void* d_ws, size_t ws_size,
                              hipStream_t stream) {
    const float* x  = (const float*)d_in[0];
    const int*   ei = (const int*)d_in[1];
    const float* W1 = (const float*)d_in[2];
    const float* b1 = (const float*)d_in[3];
    const float* W2 = (const float*)d_in[4];
    const float* b2 = (const float*)d_in[5];
    float* out = (float*)d_out;

    const int N  = in_sizes[0] / DIN;
    const int E  = in_sizes[1] / 2;
    const int NB = (N + 255) >> 8;

    char* p = (char*)d_ws;
    auto alloc = [&](size_t bytes) { void* r = p; p += (bytes + 255) & ~(size_t)255; return r; };
    float* dinv  = (float*)alloc((size_t)N * 4);
    int*   gcnt  = (int*)  alloc((size_t)NB * 4);
    int*   bbase = (int*)  alloc((size_t)NB * 4);
    int*   off   = (int*)  alloc((size_t)(N + 1) * 4);
    int*   srcs  = (int*)  alloc((size_t)E * 4);
    unsigned int* tmp = (unsigned int*)alloc((size_t)NB * BCAP * 4);
    unsigned short* wt1 = (unsigned short*)alloc(128 * 128 * 2);
    unsigned short* wt2 = (unsigned short*)alloc(64 * 128 * 2);
    unsigned char*  hs1 = (unsigned char*)alloc((size_t)N * DIN);   // fp8
    unsigned short* h1p = (unsigned short*)alloc((size_t)N * DIN * 2);
    unsigned char*  hs2 = (unsigned char*)alloc((size_t)N * NCLS);  // fp8

    wprep_k<<<64, 256, 0, stream>>>(W1, W2, wt1, wt2);
    hipMemsetAsync(gcnt, 0, (size_t)NB * 4, stream);
    binA_k<<<(E + 4095) / 4096, 256, 0, stream>>>(ei, gcnt, tmp, E, NB);
    scanb_k<<<1, 512, 0, stream>>>(gcnt, bbase, NB);
    binB_k<<<NB, 256, 0, stream>>>(tmp, gcnt, bbase, off, dinv, srcs, N, E);

    mgemm_k<DIN, true><<<(N + 127) / 128, 256, 0, stream>>>(x, wt1, dinv, hs1, SCALE1, N);
    gather1_k<<<(N + 3) / 4, 256, 0, stream>>>(hs1, off, srcs, dinv, b1, h1p, N);

    mgemm_k<NCLS, false><<<(N + 127) / 128, 256, 0, stream>>>(h1p, wt2, dinv, hs2, SCALE2, N);
    gather2_k<<<(N + 3) / 4, 256, 0, stream>>>(hs2, off, srcs, dinv, b2, out, N);
}